// Round 1
// baseline (194.146 us; speedup 1.0000x reference)
//
#include <hip/hip_runtime.h>
#include <math.h>

#define NB 4
#define NC 256
#define NHEADS 4
#define DH 64
#define NT 4096            // 64*64 tokens per batch
// q pre-scale with log2(e) folded in: exp(s/8) == exp2(s * QSCALE)
#define QSCALE (0.125f * 1.44269504088896f)

typedef __bf16  bf16x8 __attribute__((ext_vector_type(8)));
typedef __bf16  bf16x4 __attribute__((ext_vector_type(4)));
typedef float   f32x4  __attribute__((ext_vector_type(4)));
typedef float   f32x16 __attribute__((ext_vector_type(16)));
typedef short   s16x8  __attribute__((ext_vector_type(8)));
typedef unsigned int u32x4 __attribute__((ext_vector_type(4)));

static __device__ __forceinline__ unsigned short f2bf(float f) {
    unsigned u = __float_as_uint(f);
    u = (u + 0x7fffu + ((u >> 16) & 1u)) >> 16;   // round-to-nearest-even
    return (unsigned short)u;
}

// single v_exp_f32 (libm exp2f expands to a multi-inst guarded sequence)
static __device__ __forceinline__ float fast_exp2(float x) {
    return __builtin_amdgcn_exp2f(x);
}

// pack two f32 -> one dword of 2 bf16 (RNE), single instruction
static __device__ __forceinline__ unsigned cvtpk(float lo, float hi) {
    unsigned r;
    asm("v_cvt_pk_bf16_f32 %0, %1, %2" : "=v"(r) : "v"(lo), "v"(hi));
    return r;
}

// half-wave swap: a' = {a_lo, b_lo}, b' = {a_hi, b_hi} (lanes 0-31 / 32-63)
static __device__ __forceinline__ void plswap(unsigned &a, unsigned &b) {
    asm("v_permlane32_swap_b32 %0, %1" : "+v"(a), "+v"(b));
}

static __device__ __forceinline__ bf16x8 as_bf16x8(u32x4 v) {
    return __builtin_bit_cast(bf16x8, v);
}

// async 16B/lane global -> LDS (DMA, no VGPR round-trip).
static __device__ __forceinline__ void gload16(const unsigned short* g, unsigned short* l) {
    __builtin_amdgcn_global_load_lds((const __attribute__((address_space(1))) void*)g,
                                     (__attribute__((address_space(3))) void*)l, 16, 0, 0);
}

// Stage 64 rows x 256 bf16 (global row stride 256 elems) -> LDS stride 264.
static __device__ __forceinline__ void stage_64x256(
    unsigned short* __restrict__ lds, const unsigned short* __restrict__ g, int tid)
{
    #pragma unroll
    for (int chunk = 0; chunk < 8; ++chunk) {
        const int row = chunk * 8 + (tid >> 5);
        const int col = (tid & 31) * 8;
        *(s16x8*)&lds[row * 264 + col] = *(const s16x8*)&g[row * 256 + col];
    }
}

// ---------------------------------------------------------------------------
// Kernel 0: weight prep (unchanged).
// ---------------------------------------------------------------------------
__global__ __launch_bounds__(256) void k_prep(
    const float* __restrict__ wqkv, const float* __restrict__ wproj,
    unsigned short* __restrict__ wqkv_t, unsigned short* __restrict__ wproj_bf)
{
    const int id = blockIdx.x;
    const int tid = threadIdx.x;
    if (id < 48) {
        __shared__ float T[64][65];
        const int jt = id % 12, ct = id / 12;
        #pragma unroll
        for (int p = 0; p < 16; ++p) {
            const int idx = tid + (p << 8);
            const int r = idx >> 6, cl = idx & 63;
            T[r][cl] = wqkv[(size_t)(ct * 64 + r) * 768 + jt * 64 + cl];
        }
        __syncthreads();
        #pragma unroll
        for (int p = 0; p < 16; ++p) {
            const int idx = tid + (p << 8);
            const int r = idx >> 6, cl = idx & 63;
            wqkv_t[(size_t)(jt * 64 + r) * 256 + ct * 64 + cl] = f2bf(T[cl][r]);
        }
    } else {
        const int base = (id - 48) * 2048 + tid * 8;
        s16x8 v;
        #pragma unroll
        for (int j = 0; j < 8; ++j) v[j] = (short)f2bf(wproj[base + j]);
        *(s16x8*)&wproj_bf[base] = v;
    }
}

// ---------------------------------------------------------------------------
// Kernel 1: LayerNorm + QKV GEMM via bf16 MFMA. (unchanged)
// ---------------------------------------------------------------------------
__global__ __launch_bounds__(256) void k_ln_qkv(
    const float* __restrict__ x,       // [B][C][N]
    const float* __restrict__ ln_g,
    const float* __restrict__ ln_b,
    const unsigned short* __restrict__ wqkv_t,  // [768][256] bf16
    unsigned short* __restrict__ q_bf,
    unsigned short* __restrict__ k_bf,
    unsigned short* __restrict__ v_bf)
{
    __shared__ unsigned short An[64 * 264];
    __shared__ unsigned short Wt[64 * 264];
    __shared__ float red1[4][64], red2[4][64];
    __shared__ float mu_s[64], rs_s[64];

    const int b     = blockIdx.x >> 6;
    const int n0    = (blockIdx.x & 63) << 6;
    const int three = blockIdx.y;
    const int tid   = threadIdx.x;
    const int li    = tid & 63;
    const int grp   = tid >> 6;
    const int w     = grp;
    const int lane  = li;
    const int q4    = lane >> 4;
    const int c     = lane & 15;

    const float* xb = x + ((size_t)b * NC) * NT + n0 + li;

    float xr[64];
    #pragma unroll
    for (int chunk = 0; chunk < 8; ++chunk)
        #pragma unroll
        for (int j = 0; j < 8; ++j)
            xr[chunk * 8 + j] = xb[(size_t)(chunk * 32 + grp * 8 + j) * NT];

    float s1 = 0.f, s2 = 0.f;
    #pragma unroll
    for (int i = 0; i < 64; ++i) { s1 += xr[i]; s2 += xr[i] * xr[i]; }
    red1[grp][li] = s1; red2[grp][li] = s2;
    __syncthreads();
    if (tid < 64) {
        const float t1 = red1[0][tid] + red1[1][tid] + red1[2][tid] + red1[3][tid];
        const float t2 = red2[0][tid] + red2[1][tid] + red2[2][tid] + red2[3][tid];
        const float mu  = t1 * (1.0f / NC);
        const float var = t2 * (1.0f / NC) - mu * mu;
        mu_s[tid] = mu;
        rs_s[tid] = rsqrtf(var + 1e-5f);
    }
    __syncthreads();
    const float mu = mu_s[li];
    const float rs = rs_s[li];

    #pragma unroll
    for (int chunk = 0; chunk < 8; ++chunk) {
        s16x8 pk;
        #pragma unroll
        for (int j = 0; j < 8; ++j) {
            const int ch = chunk * 32 + grp * 8 + j;
            const float vv = (xr[chunk * 8 + j] - mu) * rs * ln_g[ch] + ln_b[ch];
            pk[j] = (short)f2bf(vv);
        }
        *(s16x8*)&An[li * 264 + chunk * 32 + grp * 8] = pk;
    }
    __syncthreads();

    bf16x8 aT[8];
    if (three < 2) {
        #pragma unroll
        for (int kt = 0; kt < 8; ++kt)
            aT[kt] = *(const bf16x8*)&An[(16 * w + c) * 264 + kt * 32 + q4 * 8];
    }

    for (int jt = 0; jt < 4; ++jt) {
        __syncthreads();
        stage_64x256(Wt, wqkv_t + (size_t)(three * 256 + jt * 64) * 256, tid);
        __syncthreads();

        f32x4 acc[4];
        #pragma unroll
        for (int nt = 0; nt < 4; ++nt)
            #pragma unroll
            for (int r = 0; r < 4; ++r) acc[nt][r] = 0.f;

        const int bh = b * NHEADS + jt;
        if (three < 2) {
            #pragma unroll
            for (int nt = 0; nt < 4; ++nt)
                #pragma unroll
                for (int kt = 0; kt < 8; ++kt) {
                    const bf16x8 bb = *(const bf16x8*)&Wt[(16 * nt + c) * 264 + kt * 32 + q4 * 8];
                    acc[nt] = __builtin_amdgcn_mfma_f32_16x16x32_bf16(aT[kt], bb, acc[nt], 0, 0, 0);
                }
            unsigned short* dst = (three == 0 ? q_bf : k_bf) + ((size_t)bh * NT + n0) * DH;
            const float sc = (three == 0) ? QSCALE : 1.0f;
            #pragma unroll
            for (int nt = 0; nt < 4; ++nt)
                #pragma unroll
                for (int r = 0; r < 4; ++r)
                    dst[(size_t)(16 * w + 4 * q4 + r) * DH + 16 * nt + c] = f2bf(acc[nt][r] * sc);
        } else {
            bf16x8 aW[8];
            #pragma unroll
            for (int kt = 0; kt < 8; ++kt)
                aW[kt] = *(const bf16x8*)&Wt[(16 * w + c) * 264 + kt * 32 + q4 * 8];
            #pragma unroll
            for (int nt = 0; nt < 4; ++nt)
                #pragma unroll
                for (int kt = 0; kt < 8; ++kt) {
                    const bf16x8 bb = *(const bf16x8*)&An[(16 * nt + c) * 264 + kt * 32 + q4 * 8];
                    acc[nt] = __builtin_amdgcn_mfma_f32_16x16x32_bf16(aW[kt], bb, acc[nt], 0, 0, 0);
                }
            unsigned short* dst = v_bf + (size_t)bh * DH * NT;
            #pragma unroll
            for (int nt = 0; nt < 4; ++nt)
                #pragma unroll
                for (int r = 0; r < 4; ++r)
                    dst[(size_t)(16 * w + 4 * q4 + r) * NT + n0 + 16 * nt + c] = f2bf(acc[nt][r]);
        }
    }
}

// ---------------------------------------------------------------------------
// Kernel 2: split-K flash attention, 32x32x16 MFMA, IN-REGISTER softmax.
// S^T = K Q^T (A=K m=key32, B=Q n=query32). C layout: col=lane&31=query,
// row=(r&3)+8*(r>>2)+4*hi = key. P redistribution to the PV A-operand
// (A[m=query][k=8hi+e]) is done fully in registers: v_cvt_pk_bf16_f32 pairs
// + v_permlane32_swap_b32 (half-wave exchange). No Ps LDS buffer at all.
// 32 queries/wave, 4 waves/block (128 q), 64-key double-buffered K/V tiles.
// grid = 16 bh * 32 qtiles * 2 khalf = 1024 blocks (XCD-swizzled, bijective),
// LDS = 32 KB -> 4 blocks/CU, VGPR ~110 -> 16 waves/CU (2x prior occupancy).
// ---------------------------------------------------------------------------
__global__ __launch_bounds__(256, 4) void k_attn(
    const unsigned short* __restrict__ qg,  // [bh][n][d], pre-scaled by QSCALE
    const unsigned short* __restrict__ kg,  // [bh][n][d]
    const unsigned short* __restrict__ vg,  // [bh][d][n]  (transposed)
    float* __restrict__ o_part,             // [2][16][4096][64] f32, unnormalized
    float* __restrict__ l_part)             // [2][16][4096] f32
{
    __shared__ unsigned short Ks[2 * 4096];
    __shared__ unsigned short Vt[2 * 4096];

    // bijective XCD swizzle: dispatch i -> block (i&7)*128 + (i>>3).
    // Each XCD gets a contiguous 128-block range = 2 full bh (K/V+Q ~3MB < 4MB L2).
    const int bx   = ((blockIdx.x & 7) << 7) | (blockIdx.x >> 3);
    const int bh   = bx >> 6;                  // 0..15
    const int qt   = (bx >> 1) & 31;           // 0..31
    const int kh   = bx & 1;                   // K half
    const int n0   = qt << 7;                  // 128-query tile base
    const int tid  = threadIdx.x;
    const int w    = tid >> 6;                 // wave -> queries qb..qb+31
    const int lane = tid & 63;
    const int c5   = lane & 31;
    const int hi   = lane >> 5;
    const int qb   = n0 + (w << 5);

    const unsigned short* kb = kg + ((size_t)bh * NT + (kh << 11)) * DH;
    const unsigned short* vb = vg + (size_t)bh * DH * NT + (kh << 11);

    // ---- Q frags direct from global: B-operand, lane(c5,hi) holds
    //      Q[query=qb+c5][d = 16ks + 8hi + e] ----
    bf16x8 aq[4];
    {
        const unsigned short* qrow = qg + ((size_t)bh * NT + qb + c5) * DH + hi * 8;
        #pragma unroll
        for (int ks = 0; ks < 4; ++ks)
            aq[ks] = *(const bf16x8*)(qrow + ks * 16);
    }

    // ---- staging lane geometry (per 1KB DMA instruction) ----
    const int rr = lane >> 3;                  // row within 8-row group
    const int kc = (lane & 7) ^ rr;            // swizzled 16B-chunk column
    const int koffK = rr * DH + kc * 8;

    #define ISSUE_TILE(it_, bi_)                                               \
        {                                                                      \
            const unsigned short* ktp = kb + (size_t)(it_) * 64 * DH;          \
            const unsigned short* vtp = vb + (size_t)(it_) * 64;               \
            _Pragma("unroll")                                                  \
            for (int t = 0; t < 2; ++t) {                                      \
                const int grp_ = w * 2 + t;                                    \
                gload16(ktp + grp_ * 512 + koffK,                              \
                        &Ks[(bi_) * 4096 + grp_ * 512 + lane * 8]);            \
                gload16(vtp + (size_t)(grp_ * 8 + rr) * NT + kc * 8,           \
                        &Vt[(bi_) * 4096 + grp_ * 512 + lane * 8]);            \
            }                                                                  \
        }

    ISSUE_TILE(0, 0)

    f32x16 oac[2];
    #pragma unroll
    for (int dt = 0; dt < 2; ++dt)
        #pragma unroll
        for (int r = 0; r < 16; ++r) oac[dt][r] = 0.f;
    float lsum = 0.f;   // query c5, this lane's key subset (hi-half disjoint)

    const int swz = (c5 & 7);

    for (int it = 0; it < 32; ++it) {
        const int cur = it & 1;
        asm volatile("s_waitcnt vmcnt(0)\n\ts_barrier" ::: "memory");
        if (it < 31) ISSUE_TILE(it + 1, cur ^ 1)

        const unsigned short* Kb = &Ks[cur * 4096];
        const unsigned short* Vb = &Vt[cur * 4096];

        // two 32-key sub-blocks per 64-key tile
        #pragma unroll
        for (int sb = 0; sb < 2; ++sb) {
            // ---- S^T = K Q^T over d=64 (4 k-slots of 16) ----
            f32x16 sacc;
            #pragma unroll
            for (int r = 0; r < 16; ++r) sacc[r] = 0.f;
            #pragma unroll
            for (int ks = 0; ks < 4; ++ks) {
                const bf16x8 kf = *(const bf16x8*)
                    &Kb[(sb * 32 + c5) * 64 + (((2 * ks + hi) ^ swz) << 3)];
                sacc = __builtin_amdgcn_mfma_f32_32x32x16_bf16(kf, aq[ks], sacc, 0, 0, 0);
            }

            // ---- exp (max-free, QSCALE pre-folded) + l partial, in place ----
            #pragma unroll
            for (int r = 0; r < 16; ++r) {
                sacc[r] = fast_exp2(sacc[r]);
                lsum += sacc[r];
            }

            // ---- in-register P -> PV A-fragments via cvt_pk + permlane32_swap
            // source key (rel to sb*32): kr = (r&3)+8*(r>>2)+4*hi_src
            // dest frag pa[s] elem e: key = 16*s + 8*hi + e
            unsigned X0 = cvtpk(sacc[0],  sacc[1]);
            unsigned X1 = cvtpk(sacc[4],  sacc[5]);
            plswap(X0, X1);                         // X0=dword0, X1=dword2
            unsigned X2 = cvtpk(sacc[2],  sacc[3]);
            unsigned X3 = cvtpk(sacc[6],  sacc[7]);
            plswap(X2, X3);                         // X2=dword1, X3=dword3
            const u32x4 paA = (u32x4){X0, X2, X1, X3};   // keys 16*0 +0..15

            unsigned Y0 = cvtpk(sacc[8],  sacc[9]);
            unsigned Y1 = cvtpk(sacc[12], sacc[13]);
            plswap(Y0, Y1);
            unsigned Y2 = cvtpk(sacc[10], sacc[11]);
            unsigned Y3 = cvtpk(sacc[14], sacc[15]);
            plswap(Y2, Y3);
            const u32x4 paB = (u32x4){Y0, Y2, Y1, Y3};   // keys 16*1 +0..15

            // ---- PV for this sub-block: B = V^T frags, k-slots 2sb, 2sb+1 ----
            #pragma unroll
            for (int dt = 0; dt < 2; ++dt) {
                const bf16x8 vA = *(const bf16x8*)
                    &Vb[(dt * 32 + c5) * 64 + (((4 * sb + hi) ^ swz) << 3)];
                oac[dt] = __builtin_amdgcn_mfma_f32_32x32x16_bf16(
                    as_bf16x8(paA), vA, oac[dt], 0, 0, 0);
                const bf16x8 vB = *(const bf16x8*)
                    &Vb[(dt * 32 + c5) * 64 + (((4 * sb + 2 + hi) ^ swz) << 3)];
                oac[dt] = __builtin_amdgcn_mfma_f32_32x32x16_bf16(
                    as_bf16x8(paB), vB, oac[dt], 0, 0, 0);
            }
        }
    }
    #undef ISSUE_TILE

    // ---- write unnormalized partial O (f32) and per-query l partial ----
    // C layout of PV: col=c5 -> d = 32*dt + c5, row r -> query (r&3)+8*(r>>2)+4*hi
    float* op = o_part + (((size_t)kh * 16 + bh) * NT + qb) * DH;
    #pragma unroll
    for (int dt = 0; dt < 2; ++dt)
        #pragma unroll
        for (int r = 0; r < 16; ++r) {
            const int qrow = (r & 3) + 8 * (r >> 2) + 4 * hi;
            op[(size_t)qrow * DH + 32 * dt + c5] = oac[dt][r];
        }

    float t = lsum + __shfl_xor(lsum, 32);
    if (lane < 32)
        l_part[((size_t)kh * 16 + bh) * NT + qb + c5] = t;
}

// ---------------------------------------------------------------------------
// Kernel 3: output projection via bf16 MFMA with fused split-K combine.
// (unchanged)
// ---------------------------------------------------------------------------
__global__ __launch_bounds__(256) void k_proj(
    const float* __restrict__ o_part,            // [2][16][4096][64] f32
    const float* __restrict__ l_part,            // [2][16][4096] f32
    const unsigned short* __restrict__ wproj_bf, // [256][256] bf16
    const float* __restrict__ b_proj,
    float* __restrict__ out)                     // [B][C][N]
{
    __shared__ unsigned short Os[64 * 264];
    __shared__ unsigned short Ws[64 * 264];

    const int b   = blockIdx.x >> 6;
    const int n0  = (blockIdx.x & 63) << 6;
    const int yh  = blockIdx.y;                  // 0..1 -> cg half
    const int tid = threadIdx.x;
    const int w   = tid >> 6;
    const int lane = tid & 63;
    const int q4  = lane >> 4;
    const int c   = lane & 15;

    const size_t OPS = (size_t)16 * NT * DH;     // o_part kh-stride
    const size_t LPS = (size_t)16 * NT;          // l_part kh-stride

    // ---- stage combined O tile once: (O0+O1)/(l0+l1) -> bf16 LDS ----
    #pragma unroll
    for (int chunk = 0; chunk < 8; ++chunk) {
        const int row = chunk * 8 + (tid >> 5);
        const int col = (tid & 31) * 8;
        const int hd  = col >> 6;
        const int c64 = col & 63;
        const size_t tok = (size_t)(b * NHEADS + hd) * NT + n0 + row;
        const float rv = 1.0f / (l_part[tok] + l_part[LPS + tok]);
        const float* p0 = o_part + tok * DH + c64;
        const float* p1 = p0 + OPS;
        const f32x4 a0 = *(const f32x4*)p0;
        const f32x4 a1 = *(const f32x4*)(p0 + 4);
        const f32x4 b0 = *(const f32x4*)p1;
        const f32x4 b1 = *(const f32x4*)(p1 + 4);
        s16x8 pk;
        #pragma unroll
        for (int j = 0; j < 4; ++j) {
            pk[j]     = (short)f2bf((a0[j] + b0[j]) * rv);
            pk[4 + j] = (short)f2bf((a1[j] + b1[j]) * rv);
        }
        *(s16x8*)&Os[row * 264 + col] = pk;
    }

    for (int ct = 0; ct < 2; ++ct) {
        const int cg0 = (yh * 2 + ct) * 64;
        if (ct) __syncthreads();                 // Ws reuse guard
        stage_64x256(Ws, wproj_bf + (size_t)cg0 * NC, tid);
        __syncthreads();                         // Ws (and on ct==0, Os) visible

        bf16x8 a[8];
        #pragma unroll
        for (int kt = 0; kt < 8; ++kt)
            a[kt] = *(const bf16x8*)&Ws[(16 * w + c) * 264 + kt * 32 + q4 * 8];

        f32x4 acc[4];
        #pragma unroll
        for (int nt = 0; nt < 4; ++nt)
            #pragma unroll
            for (int r = 0; r < 4; ++r) acc[nt][r] = 0.f;

        #pragma unroll
        for (int nt = 0; nt < 4; ++nt)
            #pragma unroll
            for (int kt = 0; kt < 8; ++kt) {
                const bf16x8 bb = *(const bf16x8*)&Os[(16 * nt + c) * 264 + kt * 32 + q4 * 8];
                acc[nt] = __builtin_amdgcn_mfma_f32_16x16x32_bf16(a[kt], bb, acc[nt], 0, 0, 0);
            }

        #pragma unroll
        for (int nt = 0; nt < 4; ++nt)
            #pragma unroll
            for (int r = 0; r < 4; ++r) {
                const int cg = cg0 + 16 * w + 4 * q4 + r;
                out[((size_t)b * NC + cg) * NT + n0 + 16 * nt + c] = acc[nt][r] + b_proj[cg];
            }
    }
}

// ---------------------------------------------------------------------------
extern "C" void kernel_launch(void* const* d_in, const int* in_sizes, int n_in,
                              void* d_out, int out_size, void* d_ws, size_t ws_size,
                              hipStream_t stream)
{
    const float* x      = (const float*)d_in[0];
    const float* ln_g   = (const float*)d_in[1];
    const float* ln_b   = (const float*)d_in[2];
    const float* w_qkv  = (const float*)d_in[3];
    const float* w_proj = (const float*)d_in[4];
    const float* b_proj = (const float*)d_in[5];
    float* out = (float*)d_out;

    const size_t TEN = (size_t)NB * NHEADS * NT * DH;   // 4,194,304 elements

    float* ws32 = (float*)d_ws;
    float* o_part = ws32;                                // 8,388,608 f32
    float* l_part = ws32 + 8388608;                      // 131,072 f32
    unsigned short* ws16 = (unsigned short*)(l_part + 131072);
    unsigned short* q_bf    = ws16;
    unsigned short* k_bf    = ws16 + TEN;
    unsigned short* v_bf    = ws16 + 2 * TEN;
    unsigned short* wqkv_t  = ws16 + 3 * TEN;            // [768][256]
    unsigned short* wproj_b = wqkv_t + 768 * 256;        // [256][256]

    k_prep<<<80, 256, 0, stream>>>(w_qkv, w_proj, wqkv_t, wproj_b);
    k_ln_qkv<<<dim3(NB * 64, 3), 256, 0, stream>>>(x, ln_g, ln_b, wqkv_t, q_bf, k_bf, v_bf);
    k_attn<<<16 * 64, 256, 0, stream>>>(q_bf, k_bf, v_bf, o_part, l_part);
    k_proj<<<dim3(NB * 64, 2), 256, 0, stream>>>(o_part, l_part, wproj_b, b_proj, out);
}

// Round 2
// 181.797 us; speedup vs baseline: 1.0679x; 1.0679x over previous
//
#include <hip/hip_runtime.h>
#include <math.h>

#define NB 4
#define NC 256
#define NHEADS 4
#define DH 64
#define NT 4096            // 64*64 tokens per batch
// q pre-scale with log2(e) folded in: exp(s/8) == exp2(s * QSCALE)
#define QSCALE (0.125f * 1.44269504088896f)

typedef __bf16  bf16x8 __attribute__((ext_vector_type(8)));
typedef float   f32x4  __attribute__((ext_vector_type(4)));
typedef float   f32x16 __attribute__((ext_vector_type(16)));
typedef short   s16x8  __attribute__((ext_vector_type(8)));
typedef unsigned int u32x4 __attribute__((ext_vector_type(4)));

static __device__ __forceinline__ unsigned short f2bf(float f) {
    unsigned u = __float_as_uint(f);
    u = (u + 0x7fffu + ((u >> 16) & 1u)) >> 16;   // round-to-nearest-even
    return (unsigned short)u;
}

static __device__ __forceinline__ float fast_exp2(float x) {
    return __builtin_amdgcn_exp2f(x);
}

// pack two f32 -> one dword of 2 bf16 (RNE), single instruction
static __device__ __forceinline__ unsigned cvtpk(float lo, float hi) {
    unsigned r;
    asm("v_cvt_pk_bf16_f32 %0, %1, %2" : "=v"(r) : "v"(lo), "v"(hi));
    return r;
}

// half-wave swap: a' = {a_lo, b_lo}, b' = {a_hi, b_hi} (lanes 0-31 / 32-63)
static __device__ __forceinline__ void plswap(unsigned &a, unsigned &b) {
    asm("v_permlane32_swap_b32 %0, %1" : "+v"(a), "+v"(b));
}

static __device__ __forceinline__ bf16x8 as_bf16x8(u32x4 v) {
    return __builtin_bit_cast(bf16x8, v);
}

// async 16B/lane global -> LDS (DMA, no VGPR round-trip).
static __device__ __forceinline__ void gload16(const unsigned short* g, unsigned short* l) {
    __builtin_amdgcn_global_load_lds((const __attribute__((address_space(1))) void*)g,
                                     (__attribute__((address_space(3))) void*)l, 16, 0, 0);
}

// Stage 64 rows x 256 bf16 (global row stride 256 elems) -> LDS stride 264.
static __device__ __forceinline__ void stage_64x256(
    unsigned short* __restrict__ lds, const unsigned short* __restrict__ g, int tid)
{
    #pragma unroll
    for (int chunk = 0; chunk < 8; ++chunk) {
        const int row = chunk * 8 + (tid >> 5);
        const int col = (tid & 31) * 8;
        *(s16x8*)&lds[row * 264 + col] = *(const s16x8*)&g[row * 256 + col];
    }
}

// ---------------------------------------------------------------------------
// Kernel 0: weight prep (unchanged).
// ---------------------------------------------------------------------------
__global__ __launch_bounds__(256) void k_prep(
    const float* __restrict__ wqkv, const float* __restrict__ wproj,
    unsigned short* __restrict__ wqkv_t, unsigned short* __restrict__ wproj_bf)
{
    const int id = blockIdx.x;
    const int tid = threadIdx.x;
    if (id < 48) {
        __shared__ float T[64][65];
        const int jt = id % 12, ct = id / 12;
        #pragma unroll
        for (int p = 0; p < 16; ++p) {
            const int idx = tid + (p << 8);
            const int r = idx >> 6, cl = idx & 63;
            T[r][cl] = wqkv[(size_t)(ct * 64 + r) * 768 + jt * 64 + cl];
        }
        __syncthreads();
        #pragma unroll
        for (int p = 0; p < 16; ++p) {
            const int idx = tid + (p << 8);
            const int r = idx >> 6, cl = idx & 63;
            wqkv_t[(size_t)(jt * 64 + r) * 256 + ct * 64 + cl] = f2bf(T[cl][r]);
        }
    } else {
        const int base = (id - 48) * 2048 + tid * 8;
        s16x8 v;
        #pragma unroll
        for (int j = 0; j < 8; ++j) v[j] = (short)f2bf(wproj[base + j]);
        *(s16x8*)&wproj_bf[base] = v;
    }
}

// ---------------------------------------------------------------------------
// Kernel 1: LayerNorm + QKV GEMM via bf16 MFMA. (unchanged)
// ---------------------------------------------------------------------------
__global__ __launch_bounds__(256) void k_ln_qkv(
    const float* __restrict__ x,       // [B][C][N]
    const float* __restrict__ ln_g,
    const float* __restrict__ ln_b,
    const unsigned short* __restrict__ wqkv_t,  // [768][256] bf16
    unsigned short* __restrict__ q_bf,
    unsigned short* __restrict__ k_bf,
    unsigned short* __restrict__ v_bf)
{
    __shared__ unsigned short An[64 * 264];
    __shared__ unsigned short Wt[64 * 264];
    __shared__ float red1[4][64], red2[4][64];
    __shared__ float mu_s[64], rs_s[64];

    const int b     = blockIdx.x >> 6;
    const int n0    = (blockIdx.x & 63) << 6;
    const int three = blockIdx.y;
    const int tid   = threadIdx.x;
    const int li    = tid & 63;
    const int grp   = tid >> 6;
    const int w     = grp;
    const int lane  = li;
    const int q4    = lane >> 4;
    const int c     = lane & 15;

    const float* xb = x + ((size_t)b * NC) * NT + n0 + li;

    float xr[64];
    #pragma unroll
    for (int chunk = 0; chunk < 8; ++chunk)
        #pragma unroll
        for (int j = 0; j < 8; ++j)
            xr[chunk * 8 + j] = xb[(size_t)(chunk * 32 + grp * 8 + j) * NT];

    float s1 = 0.f, s2 = 0.f;
    #pragma unroll
    for (int i = 0; i < 64; ++i) { s1 += xr[i]; s2 += xr[i] * xr[i]; }
    red1[grp][li] = s1; red2[grp][li] = s2;
    __syncthreads();
    if (tid < 64) {
        const float t1 = red1[0][tid] + red1[1][tid] + red1[2][tid] + red1[3][tid];
        const float t2 = red2[0][tid] + red2[1][tid] + red2[2][tid] + red2[3][tid];
        const float mu  = t1 * (1.0f / NC);
        const float var = t2 * (1.0f / NC) - mu * mu;
        mu_s[tid] = mu;
        rs_s[tid] = rsqrtf(var + 1e-5f);
    }
    __syncthreads();
    const float mu = mu_s[li];
    const float rs = rs_s[li];

    #pragma unroll
    for (int chunk = 0; chunk < 8; ++chunk) {
        s16x8 pk;
        #pragma unroll
        for (int j = 0; j < 8; ++j) {
            const int ch = chunk * 32 + grp * 8 + j;
            const float vv = (xr[chunk * 8 + j] - mu) * rs * ln_g[ch] + ln_b[ch];
            pk[j] = (short)f2bf(vv);
        }
        *(s16x8*)&An[li * 264 + chunk * 32 + grp * 8] = pk;
    }
    __syncthreads();

    bf16x8 aT[8];
    if (three < 2) {
        #pragma unroll
        for (int kt = 0; kt < 8; ++kt)
            aT[kt] = *(const bf16x8*)&An[(16 * w + c) * 264 + kt * 32 + q4 * 8];
    }

    for (int jt = 0; jt < 4; ++jt) {
        __syncthreads();
        stage_64x256(Wt, wqkv_t + (size_t)(three * 256 + jt * 64) * 256, tid);
        __syncthreads();

        f32x4 acc[4];
        #pragma unroll
        for (int nt = 0; nt < 4; ++nt)
            #pragma unroll
            for (int r = 0; r < 4; ++r) acc[nt][r] = 0.f;

        const int bh = b * NHEADS + jt;
        if (three < 2) {
            #pragma unroll
            for (int nt = 0; nt < 4; ++nt)
                #pragma unroll
                for (int kt = 0; kt < 8; ++kt) {
                    const bf16x8 bb = *(const bf16x8*)&Wt[(16 * nt + c) * 264 + kt * 32 + q4 * 8];
                    acc[nt] = __builtin_amdgcn_mfma_f32_16x16x32_bf16(aT[kt], bb, acc[nt], 0, 0, 0);
                }
            unsigned short* dst = (three == 0 ? q_bf : k_bf) + ((size_t)bh * NT + n0) * DH;
            const float sc = (three == 0) ? QSCALE : 1.0f;
            #pragma unroll
            for (int nt = 0; nt < 4; ++nt)
                #pragma unroll
                for (int r = 0; r < 4; ++r)
                    dst[(size_t)(16 * w + 4 * q4 + r) * DH + 16 * nt + c] = f2bf(acc[nt][r] * sc);
        } else {
            bf16x8 aW[8];
            #pragma unroll
            for (int kt = 0; kt < 8; ++kt)
                aW[kt] = *(const bf16x8*)&Wt[(16 * w + c) * 264 + kt * 32 + q4 * 8];
            #pragma unroll
            for (int nt = 0; nt < 4; ++nt)
                #pragma unroll
                for (int kt = 0; kt < 8; ++kt) {
                    const bf16x8 bb = *(const bf16x8*)&An[(16 * nt + c) * 264 + kt * 32 + q4 * 8];
                    acc[nt] = __builtin_amdgcn_mfma_f32_16x16x32_bf16(aW[kt], bb, acc[nt], 0, 0, 0);
                }
            unsigned short* dst = v_bf + (size_t)bh * DH * NT;
            #pragma unroll
            for (int nt = 0; nt < 4; ++nt)
                #pragma unroll
                for (int r = 0; r < 4; ++r)
                    dst[(size_t)(16 * w + 4 * q4 + r) * NT + n0 + 16 * nt + c] = f2bf(acc[nt][r]);
        }
    }
}

// ---------------------------------------------------------------------------
// Kernel 2: NO-split-K flash attention, 32x32x16 MFMA, in-register softmax.
// 512 blocks (16 bh x 32 qtiles of 128 q), each walks all 4096 keys in 32
// double-buffered 128-key tiles (K 16KB + V 16KB per buf -> 64KB LDS,
// 2 blocks/CU, 256-VGPR budget). Per iter: 4 key-sub-blocks processed as two
// batched pairs (two independent QK MFMA chains; PV of pair p overlaps exp of
// pair p+1). setprio(1) around MFMA clusters (T5). Writes NORMALIZED bf16 O
// directly -> no o_part/l_part f32 round-trip, no combine in k_proj.
// ---------------------------------------------------------------------------
__global__ __launch_bounds__(256, 2) void k_attn(
    const unsigned short* __restrict__ qg,  // [bh][n][d], pre-scaled by QSCALE
    const unsigned short* __restrict__ kg,  // [bh][n][d]
    const unsigned short* __restrict__ vg,  // [bh][d][n]  (transposed)
    unsigned short* __restrict__ og)        // [bh][n][d] bf16, normalized
{
    __shared__ unsigned short Ks[2 * 8192];   // 2 x (128 keys x 64 d)
    __shared__ unsigned short Vt[2 * 8192];   // 2 x (64 d x 128 keys)
    __shared__ float l_s[4][32];

    // bijective XCD swizzle: 512 = 8 XCD x 64; each XCD gets 2 contiguous bh.
    const int bx   = ((blockIdx.x & 7) << 6) | (blockIdx.x >> 3);
    const int bh   = bx >> 5;                  // 0..15
    const int qt   = bx & 31;                  // 0..31
    const int n0   = qt << 7;                  // 128-query tile base
    const int tid  = threadIdx.x;
    const int w    = tid >> 6;                 // wave -> queries qb..qb+31
    const int lane = tid & 63;
    const int c5   = lane & 31;
    const int hi   = lane >> 5;
    const int qb   = n0 + (w << 5);
    const int swz  = c5 & 7;

    const unsigned short* kb = kg + (size_t)bh * NT * DH;
    const unsigned short* vb = vg + (size_t)bh * DH * NT;

    // ---- Q frags direct from global: B-operand, lane(c5,hi) holds
    //      Q[query=qb+c5][d = 16ks + 8hi + e] ----
    bf16x8 aq[4];
    {
        const unsigned short* qrow = qg + ((size_t)bh * NT + qb + c5) * DH + hi * 8;
        #pragma unroll
        for (int ks = 0; ks < 4; ++ks)
            aq[ks] = *(const bf16x8*)(qrow + ks * 16);
    }

    // ---- staging lane geometry (per 1KB DMA instruction) ----
    // K tile rows = keys (128B each): 8 rows per 1KB group.
    const int rr  = lane >> 3;                 // row within 8-row group
    const int kcK = (lane & 7) ^ rr;           // swizzled 16B chunk (K)
    // V tile rows = d (256B each): 4 rows per 1KB group.
    const int rd  = lane >> 4;                 // d-row within 4-row group
    const int ckV = lane & 15;                 // 16B chunk within 256B row

    #define ISSUE_TILE(it_, bi_)                                               \
        {                                                                      \
            const unsigned short* ktp = kb + (size_t)(it_) * 128 * DH;         \
            const unsigned short* vtp = vb + (size_t)(it_) * 128;              \
            _Pragma("unroll")                                                  \
            for (int t = 0; t < 4; ++t) {                                      \
                const int grp_ = w * 4 + t;                                    \
                gload16(ktp + (size_t)(grp_ * 8 + rr) * DH + kcK * 8,          \
                        &Ks[(bi_) * 8192 + grp_ * 512 + lane * 8]);            \
                const int kcV_ = ckV ^ ((4 * grp_ + rd) & 7);                  \
                gload16(vtp + (size_t)(4 * grp_ + rd) * NT + kcV_ * 8,         \
                        &Vt[(bi_) * 8192 + grp_ * 512 + lane * 8]);            \
            }                                                                  \
        }

    ISSUE_TILE(0, 0)

    f32x16 oac[2];
    #pragma unroll
    for (int dt = 0; dt < 2; ++dt)
        #pragma unroll
        for (int r = 0; r < 16; ++r) oac[dt][r] = 0.f;
    float ls0 = 0.f, ls1 = 0.f, ls2 = 0.f, ls3 = 0.f;   // 4 partial l chains

    for (int it = 0; it < 32; ++it) {
        const int cur = it & 1;
        asm volatile("s_waitcnt vmcnt(0)\n\ts_barrier" ::: "memory");
        if (it < 31) ISSUE_TILE(it + 1, cur ^ 1)

        const unsigned short* Kb = &Ks[cur * 8192];
        const unsigned short* Vb = &Vt[cur * 8192];

        // four 32-key sub-blocks, processed as two batched pairs
        #pragma unroll
        for (int hf = 0; hf < 2; ++hf) {
            const int sb0 = 2 * hf, sb1 = 2 * hf + 1;

            // ---- S^T = K Q^T over d=64, two independent chains ----
            f32x16 s0, s1;
            #pragma unroll
            for (int r = 0; r < 16; ++r) { s0[r] = 0.f; s1[r] = 0.f; }
            __builtin_amdgcn_s_setprio(1);
            #pragma unroll
            for (int ks = 0; ks < 4; ++ks) {
                const bf16x8 kf0 = *(const bf16x8*)
                    &Kb[(sb0 * 32 + c5) * 64 + (((2 * ks + hi) ^ swz) << 3)];
                s0 = __builtin_amdgcn_mfma_f32_32x32x16_bf16(kf0, aq[ks], s0, 0, 0, 0);
            }
            #pragma unroll
            for (int ks = 0; ks < 4; ++ks) {
                const bf16x8 kf1 = *(const bf16x8*)
                    &Kb[(sb1 * 32 + c5) * 64 + (((2 * ks + hi) ^ swz) << 3)];
                s1 = __builtin_amdgcn_mfma_f32_32x32x16_bf16(kf1, aq[ks], s1, 0, 0, 0);
            }
            __builtin_amdgcn_s_setprio(0);

            // ---- exp (max-free) + l partials ----
            #pragma unroll
            for (int r = 0; r < 16; r += 4) {
                s0[r]   = fast_exp2(s0[r]);   ls0 += s0[r];
                s0[r+1] = fast_exp2(s0[r+1]); ls1 += s0[r+1];
                s0[r+2] = fast_exp2(s0[r+2]); ls2 += s0[r+2];
                s0[r+3] = fast_exp2(s0[r+3]); ls3 += s0[r+3];
            }
            #pragma unroll
            for (int r = 0; r < 16; r += 4) {
                s1[r]   = fast_exp2(s1[r]);   ls0 += s1[r];
                s1[r+1] = fast_exp2(s1[r+1]); ls1 += s1[r+1];
                s1[r+2] = fast_exp2(s1[r+2]); ls2 += s1[r+2];
                s1[r+3] = fast_exp2(s1[r+3]); ls3 += s1[r+3];
            }

            // ---- in-register P -> PV A-frags (cvt_pk + permlane32_swap) ----
            unsigned A0 = cvtpk(s0[0],  s0[1]),  A1 = cvtpk(s0[4],  s0[5]);
            plswap(A0, A1);
            unsigned A2 = cvtpk(s0[2],  s0[3]),  A3 = cvtpk(s0[6],  s0[7]);
            plswap(A2, A3);
            const u32x4 paA0 = (u32x4){A0, A2, A1, A3};     // sb0 keys 0..15
            unsigned B0 = cvtpk(s0[8],  s0[9]),  B1 = cvtpk(s0[12], s0[13]);
            plswap(B0, B1);
            unsigned B2 = cvtpk(s0[10], s0[11]), B3 = cvtpk(s0[14], s0[15]);
            plswap(B2, B3);
            const u32x4 paB0 = (u32x4){B0, B2, B1, B3};     // sb0 keys 16..31
            unsigned C0 = cvtpk(s1[0],  s1[1]),  C1 = cvtpk(s1[4],  s1[5]);
            plswap(C0, C1);
            unsigned C2 = cvtpk(s1[2],  s1[3]),  C3 = cvtpk(s1[6],  s1[7]);
            plswap(C2, C3);
            const u32x4 paA1 = (u32x4){C0, C2, C1, C3};     // sb1 keys 0..15
            unsigned D0 = cvtpk(s1[8],  s1[9]),  D1 = cvtpk(s1[12], s1[13]);
            plswap(D0, D1);
            unsigned D2 = cvtpk(s1[10], s1[11]), D3 = cvtpk(s1[14], s1[15]);
            plswap(D2, D3);
            const u32x4 paB1 = (u32x4){D0, D2, D1, D3};     // sb1 keys 16..31

            // ---- PV: B = V^T frags; V chunk j = 4*sb + 2*s + hi ----
            __builtin_amdgcn_s_setprio(1);
            #pragma unroll
            for (int dt = 0; dt < 2; ++dt) {
                const int rv = (dt * 32 + c5) * 128;
                const bf16x8 vA0 = *(const bf16x8*)&Vb[rv + (((4*sb0 + hi) ^ swz) << 3)];
                oac[dt] = __builtin_amdgcn_mfma_f32_32x32x16_bf16(
                    as_bf16x8(paA0), vA0, oac[dt], 0, 0, 0);
                const bf16x8 vB0 = *(const bf16x8*)&Vb[rv + (((4*sb0 + 2 + hi) ^ swz) << 3)];
                oac[dt] = __builtin_amdgcn_mfma_f32_32x32x16_bf16(
                    as_bf16x8(paB0), vB0, oac[dt], 0, 0, 0);
                const bf16x8 vA1 = *(const bf16x8*)&Vb[rv + (((4*sb1 + hi) ^ swz) << 3)];
                oac[dt] = __builtin_amdgcn_mfma_f32_32x32x16_bf16(
                    as_bf16x8(paA1), vA1, oac[dt], 0, 0, 0);
                const bf16x8 vB1 = *(const bf16x8*)&Vb[rv + (((4*sb1 + 2 + hi) ^ swz) << 3)];
                oac[dt] = __builtin_amdgcn_mfma_f32_32x32x16_bf16(
                    as_bf16x8(paB1), vB1, oac[dt], 0, 0, 0);
            }
            __builtin_amdgcn_s_setprio(0);
        }
    }
    #undef ISSUE_TILE

    // ---- per-query l: query c5 owned by this wave; redistribute via LDS ----
    const float lsum = (ls0 + ls1) + (ls2 + ls3);
    const float t = lsum + __shfl_xor(lsum, 32);
    if (lane < 32) l_s[w][c5] = t;
    __syncthreads();

    // ---- normalize + write bf16 O: row r -> query (r&3)+8*(r>>2)+4*hi ----
    unsigned short* ob = og + ((size_t)bh * NT + qb) * DH;
    #pragma unroll
    for (int r = 0; r < 16; ++r) {
        const int qrow = (r & 3) + 8 * (r >> 2) + 4 * hi;
        const float rn = 1.0f / l_s[w][qrow];
        ob[(size_t)qrow * DH + c5]      = f2bf(oac[0][r] * rn);
        ob[(size_t)qrow * DH + 32 + c5] = f2bf(oac[1][r] * rn);
    }
}

// ---------------------------------------------------------------------------
// Kernel 3: output projection via bf16 MFMA. O arrives normalized bf16 ->
// staging is a straight 16B copy (no split-K combine, no f32 traffic).
// ---------------------------------------------------------------------------
__global__ __launch_bounds__(256) void k_proj(
    const unsigned short* __restrict__ o_bf,     // [bh][n][64] bf16 normalized
    const unsigned short* __restrict__ wproj_bf, // [256][256] bf16
    const float* __restrict__ b_proj,
    float* __restrict__ out)                     // [B][C][N]
{
    __shared__ unsigned short Os[64 * 264];
    __shared__ unsigned short Ws[64 * 264];

    const int b   = blockIdx.x >> 6;
    const int n0  = (blockIdx.x & 63) << 6;
    const int yh  = blockIdx.y;                  // 0..1 -> cg half
    const int tid = threadIdx.x;
    const int w   = tid >> 6;
    const int lane = tid & 63;
    const int q4  = lane >> 4;
    const int c   = lane & 15;

    // ---- stage O tile: [token][c = hd*64 + d] bf16, direct 16B copies ----
    #pragma unroll
    for (int chunk = 0; chunk < 8; ++chunk) {
        const int row = chunk * 8 + (tid >> 5);
        const int col = (tid & 31) * 8;
        const int hd  = col >> 6;
        const int c64 = col & 63;
        const unsigned short* src =
            &o_bf[((size_t)(b * NHEADS + hd) * NT + n0 + row) * DH + c64];
        *(s16x8*)&Os[row * 264 + col] = *(const s16x8*)src;
    }

    for (int ct = 0; ct < 2; ++ct) {
        const int cg0 = (yh * 2 + ct) * 64;
        if (ct) __syncthreads();                 // Ws reuse guard
        stage_64x256(Ws, wproj_bf + (size_t)cg0 * NC, tid);
        __syncthreads();                         // Ws (and on ct==0, Os) visible

        bf16x8 a[8];
        #pragma unroll
        for (int kt = 0; kt < 8; ++kt)
            a[kt] = *(const bf16x8*)&Ws[(16 * w + c) * 264 + kt * 32 + q4 * 8];

        f32x4 acc[4];
        #pragma unroll
        for (int nt = 0; nt < 4; ++nt)
            #pragma unroll
            for (int r = 0; r < 4; ++r) acc[nt][r] = 0.f;

        #pragma unroll
        for (int nt = 0; nt < 4; ++nt)
            #pragma unroll
            for (int kt = 0; kt < 8; ++kt) {
                const bf16x8 bb = *(const bf16x8*)&Os[(16 * nt + c) * 264 + kt * 32 + q4 * 8];
                acc[nt] = __builtin_amdgcn_mfma_f32_16x16x32_bf16(a[kt], bb, acc[nt], 0, 0, 0);
            }

        #pragma unroll
        for (int nt = 0; nt < 4; ++nt)
            #pragma unroll
            for (int r = 0; r < 4; ++r) {
                const int cg = cg0 + 16 * w + 4 * q4 + r;
                out[((size_t)b * NC + cg) * NT + n0 + 16 * nt + c] = acc[nt][r] + b_proj[cg];
            }
    }
}

// ---------------------------------------------------------------------------
extern "C" void kernel_launch(void* const* d_in, const int* in_sizes, int n_in,
                              void* d_out, int out_size, void* d_ws, size_t ws_size,
                              hipStream_t stream)
{
    const float* x      = (const float*)d_in[0];
    const float* ln_g   = (const float*)d_in[1];
    const float* ln_b   = (const float*)d_in[2];
    const float* w_qkv  = (const float*)d_in[3];
    const float* w_proj = (const float*)d_in[4];
    const float* b_proj = (const float*)d_in[5];
    float* out = (float*)d_out;

    const size_t TEN = (size_t)NB * NHEADS * NT * DH;   // 4,194,304 elements

    unsigned short* ws16 = (unsigned short*)d_ws;
    unsigned short* q_bf    = ws16;
    unsigned short* k_bf    = ws16 + TEN;
    unsigned short* v_bf    = ws16 + 2 * TEN;
    unsigned short* o_bf    = ws16 + 3 * TEN;
    unsigned short* wqkv_t  = ws16 + 4 * TEN;            // [768][256]
    unsigned short* wproj_b = wqkv_t + 768 * 256;        // [256][256]

    k_prep<<<80, 256, 0, stream>>>(w_qkv, w_proj, wqkv_t, wproj_b);
    k_ln_qkv<<<dim3(NB * 64, 3), 256, 0, stream>>>(x, ln_g, ln_b, wqkv_t, q_bf, k_bf, v_bf);
    k_attn<<<512, 256, 0, stream>>>(q_bf, k_bf, v_bf, o_bf);
    k_proj<<<dim3(NB * 64, 2), 256, 0, stream>>>(o_bf, wproj_b, b_proj, out);
}